// Round 1
// baseline (1857.879 us; speedup 1.0000x reference)
//
#include <hip/hip_runtime.h>
#include <hip/hip_bf16.h>
#include <cstdint>
#include <cstddef>

#define D_DIM 1024
#define VOCAB 32000
#define ROWS  4096      // 16*256
#define CHUNK 3200      // V-slab; 32000 = 10*3200, 3200 % 128 == 0
#define NCHUNK 10

typedef __attribute__((ext_vector_type(8))) short bf16x8;   // 8 bf16 = 4 VGPRs (MFMA A/B frag)
typedef __attribute__((ext_vector_type(4))) float f32x4;    // MFMA C/D frag

// float -> bf16 bits, round-to-nearest-even
static __device__ __forceinline__ unsigned short f2bf(float f) {
  union { float f; unsigned int u; } c; c.f = f;
  unsigned int u = c.u;
  u += 0x7fffu + ((u >> 16) & 1u);
  return (unsigned short)(u >> 16);
}

// async global->LDS, 16B per lane. LDS base must be wave-uniform; data lands at base + lane*16.
static __device__ __forceinline__ void gload_lds16(const void* g, void* s) {
  __builtin_amdgcn_global_load_lds(
      (const __attribute__((address_space(1))) uint32_t*)(g),
      (__attribute__((address_space(3))) uint32_t*)(s), 16, 0, 0);
}

// ---------------------------------------------------------------------------
// fp32 -> bf16 convert (4 elems/thread)
__global__ void k_cvt(const float* __restrict__ src, short* __restrict__ dst, int n4) {
  int i = blockIdx.x * 256 + threadIdx.x;
  if (i < n4) {
    float4 v = *(const float4*)(src + (size_t)i * 4);
    ushort4 u;
    u.x = f2bf(v.x); u.y = f2bf(v.y); u.z = f2bf(v.z); u.w = f2bf(v.w);
    *(ushort4*)(dst + (size_t)i * 4) = u;
  }
}

// ---------------------------------------------------------------------------
// tiled transpose: src[R][C] fp32 -> dst[C][R] bf16
__global__ void k_transpose(const float* __restrict__ src, short* __restrict__ dst,
                            int R, int C) {
  __shared__ float tile[32][33];
  int tx = threadIdx.x;           // 0..31
  int ty = threadIdx.y;           // 0..7
  int r0 = blockIdx.x * 32;
  int c0 = blockIdx.y * 32;
#pragma unroll
  for (int j = 0; j < 32; j += 8)
    tile[ty + j][tx] = src[(size_t)(r0 + ty + j) * C + c0 + tx];
  __syncthreads();
#pragma unroll
  for (int j = 0; j < 32; j += 8)
    dst[(size_t)(c0 + ty + j) * R + r0 + tx] = (short)f2bf(tile[tx][ty + j]);
}

// ---------------------------------------------------------------------------
// bf16 GEMM, C[M x N] = A[M x K] * B^T where B stored [N x K] (k-contiguous).
// 128x128 tile, BK=64, 256 threads (4 waves, each 64x64 via 4x4 of 16x16x32 MFMA).
// mode 0: Pout = exp(C) (bf16), den[row] += rowsum(exp) (atomic)
// mode 1: Cacc = (accumulate ? Cacc : 0) + C          (ldc = 1024)
// mode 2: Cout = C + bias[col] + resid[row*1024+col]  (ldc = 1024)
__global__ __launch_bounds__(256) void k_gemm(
    const short* __restrict__ A, int lda,
    const short* __restrict__ B, int ldb,
    int Kdim, int mode,
    short* __restrict__ Pout, int ldp, float* __restrict__ den,
    float* __restrict__ Cacc, int accumulate,
    const float* __restrict__ bias, const float* __restrict__ resid,
    float* __restrict__ Cout)
{
  __shared__ short As[128 * 64];
  __shared__ short Bs[128 * 64];

  int tid  = threadIdx.x;
  int wave = tid >> 6;
  int lane = tid & 63;
  int quad = lane >> 4;
  int t16  = lane & 15;
  int wy = wave >> 1, wx = wave & 1;

  long mBase = (long)blockIdx.y * 128;
  long nBase = (long)blockIdx.x * 128;

  const short* Ab = A + (size_t)mBase * lda;
  const short* Bb = B + (size_t)nBase * ldb;
  int lrow = lane >> 3;          // 0..7
  int lcol = (lane & 7) * 8;     // 0..56

  f32x4 acc[4][4];
#pragma unroll
  for (int i = 0; i < 4; ++i)
#pragma unroll
    for (int j = 0; j < 4; ++j) acc[i][j] = (f32x4){0.f, 0.f, 0.f, 0.f};

  for (int kk = 0; kk < Kdim; kk += 64) {
    // stage 128x64 A-tile and B-tile; each wave: 32 rows of each, 4 issues x 8 rows
#pragma unroll
    for (int i = 0; i < 4; ++i) {
      int row = wave * 32 + i * 8;
      gload_lds16(Ab + (size_t)(row + lrow) * lda + kk + lcol, &As[row * 64]);
      gload_lds16(Bb + (size_t)(row + lrow) * ldb + kk + lcol, &Bs[row * 64]);
    }
    __syncthreads();
#pragma unroll
    for (int ks = 0; ks < 64; ks += 32) {
      bf16x8 af[4], bfr[4];
#pragma unroll
      for (int mi = 0; mi < 4; ++mi)
        af[mi] = *(const bf16x8*)&As[(wy * 64 + mi * 16 + t16) * 64 + ks + quad * 8];
#pragma unroll
      for (int ni = 0; ni < 4; ++ni)
        bfr[ni] = *(const bf16x8*)&Bs[(wx * 64 + ni * 16 + t16) * 64 + ks + quad * 8];
#pragma unroll
      for (int mi = 0; mi < 4; ++mi)
#pragma unroll
        for (int ni = 0; ni < 4; ++ni)
          acc[mi][ni] = __builtin_amdgcn_mfma_f32_16x16x32_bf16(af[mi], bfr[ni],
                                                                acc[mi][ni], 0, 0, 0);
    }
    __syncthreads();
  }

  // epilogue. C/D layout: row = quad*4 + r, col = t16 (within 16x16 tile)
  if (mode == 0) {
    float rsum[4][4];
#pragma unroll
    for (int mi = 0; mi < 4; ++mi)
#pragma unroll
      for (int r = 0; r < 4; ++r) rsum[mi][r] = 0.f;
#pragma unroll
    for (int mi = 0; mi < 4; ++mi) {
      long row = mBase + wy * 64 + mi * 16 + quad * 4;
#pragma unroll
      for (int ni = 0; ni < 4; ++ni) {
        long col = nBase + wx * 64 + ni * 16 + t16;
#pragma unroll
        for (int r = 0; r < 4; ++r) {
          float e = __expf(acc[mi][ni][r]);
          Pout[(size_t)(row + r) * ldp + col] = (short)f2bf(e);
          rsum[mi][r] += e;
        }
      }
    }
#pragma unroll
    for (int mi = 0; mi < 4; ++mi)
#pragma unroll
      for (int r = 0; r < 4; ++r) {
        float s = rsum[mi][r];
        s += __shfl_xor(s, 1);
        s += __shfl_xor(s, 2);
        s += __shfl_xor(s, 4);
        s += __shfl_xor(s, 8);
        if (t16 == 0)
          atomicAdd(&den[mBase + wy * 64 + mi * 16 + quad * 4 + r], s);
      }
  } else if (mode == 1) {
#pragma unroll
    for (int mi = 0; mi < 4; ++mi) {
      long row = mBase + wy * 64 + mi * 16 + quad * 4;
#pragma unroll
      for (int ni = 0; ni < 4; ++ni) {
        long col = nBase + wx * 64 + ni * 16 + t16;
#pragma unroll
        for (int r = 0; r < 4; ++r) {
          size_t idx = (size_t)(row + r) * 1024 + col;
          float prev = accumulate ? Cacc[idx] : 0.f;
          Cacc[idx] = prev + acc[mi][ni][r];
        }
      }
    }
  } else {
#pragma unroll
    for (int mi = 0; mi < 4; ++mi) {
      long row = mBase + wy * 64 + mi * 16 + quad * 4;
#pragma unroll
      for (int ni = 0; ni < 4; ++ni) {
        long col = nBase + wx * 64 + ni * 16 + t16;
#pragma unroll
        for (int r = 0; r < 4; ++r) {
          size_t idx = (size_t)(row + r) * 1024 + col;
          Cout[idx] = acc[mi][ni][r] + bias[col] + resid[idx];
        }
      }
    }
  }
}

// ---------------------------------------------------------------------------
// reprog_bf16 = bf16(num / den[row]); 4 elems/thread, 4 | 1024 so row uniform
__global__ void k_div(const float* __restrict__ num, const float* __restrict__ den,
                      short* __restrict__ out) {
  int i = (blockIdx.x * 256 + threadIdx.x) * 4;
  float4 v = *(const float4*)(num + i);
  float inv = 1.0f / den[i >> 10];
  ushort4 u;
  u.x = f2bf(v.x * inv); u.y = f2bf(v.y * inv);
  u.z = f2bf(v.z * inv); u.w = f2bf(v.w * inv);
  *(ushort4*)(out + i) = u;
}

// ---------------------------------------------------------------------------
// per-row LayerNorm over 1024 cols; one block (256 thr) per row
__global__ __launch_bounds__(256) void k_ln(const float* __restrict__ x,
                                            const float* __restrict__ gamma,
                                            const float* __restrict__ beta,
                                            float* __restrict__ out) {
  __shared__ float s_sum[4], s_sq[4];
  int row = blockIdx.x;
  int tid = threadIdx.x;
  const float* xr = x + (size_t)row * 1024;
  float4 v = *(const float4*)(xr + tid * 4);
  float s = v.x + v.y + v.z + v.w;
  float q = v.x * v.x + v.y * v.y + v.z * v.z + v.w * v.w;
#pragma unroll
  for (int off = 32; off >= 1; off >>= 1) {
    s += __shfl_down(s, off);
    q += __shfl_down(q, off);
  }
  int wv = tid >> 6;
  if ((tid & 63) == 0) { s_sum[wv] = s; s_sq[wv] = q; }
  __syncthreads();
  float tot  = s_sum[0] + s_sum[1] + s_sum[2] + s_sum[3];
  float totq = s_sq[0] + s_sq[1] + s_sq[2] + s_sq[3];
  float mu   = tot * (1.0f / 1024.0f);
  float var  = totq * (1.0f / 1024.0f) - mu * mu;
  float rstd = rsqrtf(var + 1e-5f);
  float4 g = *(const float4*)(gamma + tid * 4);
  float4 b = *(const float4*)(beta + tid * 4);
  float4 o;
  o.x = (v.x - mu) * rstd * g.x + b.x;
  o.y = (v.y - mu) * rstd * g.y + b.y;
  o.z = (v.z - mu) * rstd * g.z + b.z;
  o.w = (v.w - mu) * rstd * g.w + b.w;
  *(float4*)(out + (size_t)row * 1024 + tid * 4) = o;
}

// ---------------------------------------------------------------------------
extern "C" void kernel_launch(void* const* d_in, const int* in_sizes, int n_in,
                              void* d_out, int out_size, void* d_ws, size_t ws_size,
                              hipStream_t stream) {
  const float* patch = (const float*)d_in[0];   // [16,256,1024] = [4096,1024]
  const float* proto = (const float*)d_in[1];   // [32000,1024]
  const float* W     = (const float*)d_in[2];   // [1024,1024] (e-major, d-contig)
  const float* bvec  = (const float*)d_in[3];   // [1024]
  const float* gamma = (const float*)d_in[4];   // [1024]
  const float* beta  = (const float*)d_in[5];   // [1024]
  float* out = (float*)d_out;

  char* ws = (char*)d_ws;
  size_t off = 0;
  short* Q   = (short*)(ws + off); off += (size_t)ROWS * D_DIM * 2;    //  8 MB  bf16 Q
  short* Kb  = (short*)(ws + off); off += (size_t)VOCAB * D_DIM * 2;   // 64 MB  bf16 K [v][d]
  short* KT  = (short*)(ws + off); off += (size_t)VOCAB * D_DIM * 2;   // 64 MB  bf16 K^T [d][v]
  short* Wb  = (short*)(ws + off); off += (size_t)D_DIM * D_DIM * 2;   //  2 MB  bf16 W
  short* P   = (short*)(ws + off); off += (size_t)ROWS * CHUNK * 2;    // 26 MB  bf16 P slab
  float* num = (float*)(ws + off); off += (size_t)ROWS * D_DIM * 4;    // 16 MB  fp32 numerator
  float* den = (float*)(ws + off); off += (size_t)ROWS * 4;            // 16 KB  fp32 denominator
  float* pre = (float*)P;   // reuse P slab for pre-LN buffer (16 MB <= 26 MB)
  short* Rb  = Q;           // reuse Q region for reprogrammed bf16 (written after last GEMM1)

  hipMemsetAsync(den, 0, ROWS * sizeof(float), stream);

  k_cvt<<<ROWS * D_DIM / 4 / 256, 256, 0, stream>>>(patch, Q, ROWS * D_DIM / 4);
  k_cvt<<<VOCAB * D_DIM / 4 / 256, 256, 0, stream>>>(proto, Kb, VOCAB * D_DIM / 4);
  k_cvt<<<D_DIM * D_DIM / 4 / 256, 256, 0, stream>>>(W, Wb, D_DIM * D_DIM / 4);
  k_transpose<<<dim3(VOCAB / 32, D_DIM / 32), dim3(32, 8), 0, stream>>>(proto, KT, VOCAB, D_DIM);

  for (int c = 0; c < NCHUNK; ++c) {
    // P = exp(Q @ K_chunk^T), den += rowsum  — M=4096 N=3200 K=1024
    k_gemm<<<dim3(CHUNK / 128, ROWS / 128), 256, 0, stream>>>(
        Q, D_DIM, Kb + (size_t)c * CHUNK * D_DIM, D_DIM, D_DIM, 0,
        P, CHUNK, den, nullptr, 0, nullptr, nullptr, nullptr);
    // num (+)= P @ K_chunk — M=4096 N=1024 K=3200; B^T form from KT slice
    k_gemm<<<dim3(D_DIM / 128, ROWS / 128), 256, 0, stream>>>(
        P, CHUNK, KT + (size_t)c * CHUNK, VOCAB, CHUNK, 1,
        nullptr, 0, nullptr, num, (c > 0) ? 1 : 0, nullptr, nullptr, nullptr);
  }

  k_div<<<ROWS * D_DIM / 4 / 256, 256, 0, stream>>>(num, den, Rb);

  // pre = reprog @ W^T + b + patch — M=4096 N=1024 K=1024
  k_gemm<<<dim3(D_DIM / 128, ROWS / 128), 256, 0, stream>>>(
      Rb, D_DIM, Wb, D_DIM, D_DIM, 2,
      nullptr, 0, nullptr, nullptr, 0, bvec, patch, pre);

  k_ln<<<ROWS, 256, 0, stream>>>(pre, gamma, beta, out);
}

// Round 2
// 1493.860 us; speedup vs baseline: 1.2437x; 1.2437x over previous
//
#include <hip/hip_runtime.h>
#include <hip/hip_bf16.h>
#include <cstdint>
#include <cstddef>

#define D_DIM 1024
#define VOCAB 32000
#define ROWS  4096      // 16*256
#define CHUNK 3200      // V-slab; 32000 = 10*3200, 3200 % 128 == 0
#define NCHUNK 10

typedef __attribute__((ext_vector_type(8))) short bf16x8;   // 8 bf16 = 4 VGPRs (MFMA A/B frag)
typedef __attribute__((ext_vector_type(4))) float f32x4;    // MFMA C/D frag

// float -> bf16 bits, round-to-nearest-even
static __device__ __forceinline__ unsigned short f2bf(float f) {
  union { float f; unsigned int u; } c; c.f = f;
  unsigned int u = c.u;
  u += 0x7fffu + ((u >> 16) & 1u);
  return (unsigned short)(u >> 16);
}

// async global->LDS, 16B per lane. LDS base must be wave-uniform; data lands at base + lane*16.
static __device__ __forceinline__ void gload_lds16(const void* g, void* s) {
  __builtin_amdgcn_global_load_lds(
      (const __attribute__((address_space(1))) uint32_t*)(g),
      (__attribute__((address_space(3))) uint32_t*)(s), 16, 0, 0);
}

// ---------------------------------------------------------------------------
// fp32 -> bf16 convert (4 elems/thread)
__global__ void k_cvt(const float* __restrict__ src, short* __restrict__ dst, int n4) {
  int i = blockIdx.x * 256 + threadIdx.x;
  if (i < n4) {
    float4 v = *(const float4*)(src + (size_t)i * 4);
    ushort4 u;
    u.x = f2bf(v.x); u.y = f2bf(v.y); u.z = f2bf(v.z); u.w = f2bf(v.w);
    *(ushort4*)(dst + (size_t)i * 4) = u;
  }
}

// ---------------------------------------------------------------------------
// tiled transpose: src[R][C] fp32 -> dst[C][R] bf16
__global__ void k_transpose(const float* __restrict__ src, short* __restrict__ dst,
                            int R, int C) {
  __shared__ float tile[32][33];
  int tx = threadIdx.x;           // 0..31
  int ty = threadIdx.y;           // 0..7
  int r0 = blockIdx.x * 32;
  int c0 = blockIdx.y * 32;
#pragma unroll
  for (int j = 0; j < 32; j += 8)
    tile[ty + j][tx] = src[(size_t)(r0 + ty + j) * C + c0 + tx];
  __syncthreads();
#pragma unroll
  for (int j = 0; j < 32; j += 8)
    dst[(size_t)(c0 + ty + j) * R + r0 + tx] = (short)f2bf(tile[tx][ty + j]);
}

// ---------------------------------------------------------------------------
// bf16 GEMM, C[M x N] = A[M x K_total] * B^T where B stored [N x K_total]
// (k-contiguous). Kdim = per-z-split K range; k0 = blockIdx.z * Kdim.
// 128x128 tile, BK=64, 256 threads (4 waves, each 64x64 via 4x4 of 16x16x32 MFMA).
// LDS tiles are XOR-swizzled by 16B chunk: LDS[row][chunk j] = global chunk j^(row&7)
// -> fragment reads spread the wave over all 32 banks (2-way min aliasing = free).
// mode 0: Pout = exp(C) (bf16), den[row] += rowsum(exp) (atomic)
// mode 1: num[row*1024+col] += C (fp32 atomicAdd; num pre-zeroed; split-K safe)
// mode 2: Cout = C + bias[col] + resid[row*1024+col]  (ldc = 1024)
__global__ __launch_bounds__(256) void k_gemm(
    const short* __restrict__ A, int lda,
    const short* __restrict__ B, int ldb,
    int Kdim, int mode,
    short* __restrict__ Pout, int ldp, float* __restrict__ den,
    float* __restrict__ Cacc,
    const float* __restrict__ bias, const float* __restrict__ resid,
    float* __restrict__ Cout)
{
  __shared__ short As[128 * 64];
  __shared__ short Bs[128 * 64];

  int tid  = threadIdx.x;
  int wave = tid >> 6;
  int lane = tid & 63;
  int quad = lane >> 4;
  int t16  = lane & 15;
  int wy = wave >> 1, wx = wave & 1;

  long mBase = (long)blockIdx.y * 128;
  long nBase = (long)blockIdx.x * 128;
  int  k0    = blockIdx.z * Kdim;

  const short* Ab = A + (size_t)mBase * lda + k0;
  const short* Bb = B + (size_t)nBase * ldb + k0;
  int lrow = lane >> 3;                      // 0..7
  int lcol = ((lane & 7) ^ lrow) * 8;        // swizzled source 16B-chunk

  f32x4 acc[4][4];
#pragma unroll
  for (int i = 0; i < 4; ++i)
#pragma unroll
    for (int j = 0; j < 4; ++j) acc[i][j] = (f32x4){0.f, 0.f, 0.f, 0.f};

  int sw = t16 & 7;                          // swizzle key for fragment reads

  for (int kk = 0; kk < Kdim; kk += 64) {
    // stage 128x64 A-tile and B-tile; each wave: 32 rows of each, 4 issues x 8 rows
#pragma unroll
    for (int i = 0; i < 4; ++i) {
      int row = wave * 32 + i * 8;
      gload_lds16(Ab + (size_t)(row + lrow) * lda + kk + lcol, &As[row * 64]);
      gload_lds16(Bb + (size_t)(row + lrow) * ldb + kk + lcol, &Bs[row * 64]);
    }
    __syncthreads();
#pragma unroll
    for (int kc = 0; kc < 8; kc += 4) {      // kc = base 16B-chunk (= ks/8), ks in {0,32}
      bf16x8 af[4], bfr[4];
#pragma unroll
      for (int mi = 0; mi < 4; ++mi)
        af[mi] = *(const bf16x8*)&As[(wy * 64 + mi * 16 + t16) * 64 +
                                     (((kc + quad) ^ sw) << 3)];
#pragma unroll
      for (int ni = 0; ni < 4; ++ni)
        bfr[ni] = *(const bf16x8*)&Bs[(wx * 64 + ni * 16 + t16) * 64 +
                                      (((kc + quad) ^ sw) << 3)];
#pragma unroll
      for (int mi = 0; mi < 4; ++mi)
#pragma unroll
        for (int ni = 0; ni < 4; ++ni)
          acc[mi][ni] = __builtin_amdgcn_mfma_f32_16x16x32_bf16(af[mi], bfr[ni],
                                                                acc[mi][ni], 0, 0, 0);
    }
    __syncthreads();
  }

  // epilogue. C/D layout: row = quad*4 + r, col = t16 (within 16x16 tile)
  if (mode == 0) {
    float rsum[4][4];
#pragma unroll
    for (int mi = 0; mi < 4; ++mi)
#pragma unroll
      for (int r = 0; r < 4; ++r) rsum[mi][r] = 0.f;
#pragma unroll
    for (int mi = 0; mi < 4; ++mi) {
      long row = mBase + wy * 64 + mi * 16 + quad * 4;
#pragma unroll
      for (int ni = 0; ni < 4; ++ni) {
        long col = nBase + wx * 64 + ni * 16 + t16;
#pragma unroll
        for (int r = 0; r < 4; ++r) {
          float e = __expf(acc[mi][ni][r]);
          Pout[(size_t)(row + r) * ldp + col] = (short)f2bf(e);
          rsum[mi][r] += e;
        }
      }
    }
#pragma unroll
    for (int mi = 0; mi < 4; ++mi)
#pragma unroll
      for (int r = 0; r < 4; ++r) {
        float s = rsum[mi][r];
        s += __shfl_xor(s, 1);
        s += __shfl_xor(s, 2);
        s += __shfl_xor(s, 4);
        s += __shfl_xor(s, 8);
        if (t16 == 0)
          atomicAdd(&den[mBase + wy * 64 + mi * 16 + quad * 4 + r], s);
      }
  } else if (mode == 1) {
#pragma unroll
    for (int mi = 0; mi < 4; ++mi) {
      long row = mBase + wy * 64 + mi * 16 + quad * 4;
#pragma unroll
      for (int ni = 0; ni < 4; ++ni) {
        long col = nBase + wx * 64 + ni * 16 + t16;
#pragma unroll
        for (int r = 0; r < 4; ++r) {
          size_t idx = (size_t)(row + r) * 1024 + col;
          atomicAdd(&Cacc[idx], acc[mi][ni][r]);
        }
      }
    }
  } else {
#pragma unroll
    for (int mi = 0; mi < 4; ++mi) {
      long row = mBase + wy * 64 + mi * 16 + quad * 4;
#pragma unroll
      for (int ni = 0; ni < 4; ++ni) {
        long col = nBase + wx * 64 + ni * 16 + t16;
#pragma unroll
        for (int r = 0; r < 4; ++r) {
          size_t idx = (size_t)(row + r) * 1024 + col;
          Cout[idx] = acc[mi][ni][r] + bias[col] + resid[idx];
        }
      }
    }
  }
}

// ---------------------------------------------------------------------------
// reprog_bf16 = bf16(num / den[row]); 4 elems/thread, 4 | 1024 so row uniform
__global__ void k_div(const float* __restrict__ num, const float* __restrict__ den,
                      short* __restrict__ out) {
  int i = (blockIdx.x * 256 + threadIdx.x) * 4;
  float4 v = *(const float4*)(num + i);
  float inv = 1.0f / den[i >> 10];
  ushort4 u;
  u.x = f2bf(v.x * inv); u.y = f2bf(v.y * inv);
  u.z = f2bf(v.z * inv); u.w = f2bf(v.w * inv);
  *(ushort4*)(out + i) = u;
}

// ---------------------------------------------------------------------------
// per-row LayerNorm over 1024 cols; one block (256 thr) per row
__global__ __launch_bounds__(256) void k_ln(const float* __restrict__ x,
                                            const float* __restrict__ gamma,
                                            const float* __restrict__ beta,
                                            float* __restrict__ out) {
  __shared__ float s_sum[4], s_sq[4];
  int row = blockIdx.x;
  int tid = threadIdx.x;
  const float* xr = x + (size_t)row * 1024;
  float4 v = *(const float4*)(xr + tid * 4);
  float s = v.x + v.y + v.z + v.w;
  float q = v.x * v.x + v.y * v.y + v.z * v.z + v.w * v.w;
#pragma unroll
  for (int off = 32; off >= 1; off >>= 1) {
    s += __shfl_down(s, off);
    q += __shfl_down(q, off);
  }
  int wv = tid >> 6;
  if ((tid & 63) == 0) { s_sum[wv] = s; s_sq[wv] = q; }
  __syncthreads();
  float tot  = s_sum[0] + s_sum[1] + s_sum[2] + s_sum[3];
  float totq = s_sq[0] + s_sq[1] + s_sq[2] + s_sq[3];
  float mu   = tot * (1.0f / 1024.0f);
  float var  = totq * (1.0f / 1024.0f) - mu * mu;
  float rstd = rsqrtf(var + 1e-5f);
  float4 g = *(const float4*)(gamma + tid * 4);
  float4 b = *(const float4*)(beta + tid * 4);
  float4 o;
  o.x = (v.x - mu) * rstd * g.x + b.x;
  o.y = (v.y - mu) * rstd * g.y + b.y;
  o.z = (v.z - mu) * rstd * g.z + b.z;
  o.w = (v.w - mu) * rstd * g.w + b.w;
  *(float4*)(out + (size_t)row * 1024 + tid * 4) = o;
}

// ---------------------------------------------------------------------------
extern "C" void kernel_launch(void* const* d_in, const int* in_sizes, int n_in,
                              void* d_out, int out_size, void* d_ws, size_t ws_size,
                              hipStream_t stream) {
  const float* patch = (const float*)d_in[0];   // [16,256,1024] = [4096,1024]
  const float* proto = (const float*)d_in[1];   // [32000,1024]
  const float* W     = (const float*)d_in[2];   // [1024,1024] (e-major, d-contig)
  const float* bvec  = (const float*)d_in[3];   // [1024]
  const float* gamma = (const float*)d_in[4];   // [1024]
  const float* beta  = (const float*)d_in[5];   // [1024]
  float* out = (float*)d_out;

  char* ws = (char*)d_ws;
  size_t off = 0;
  short* Q   = (short*)(ws + off); off += (size_t)ROWS * D_DIM * 2;    //  8 MB  bf16 Q
  short* Kb  = (short*)(ws + off); off += (size_t)VOCAB * D_DIM * 2;   // 64 MB  bf16 K [v][d]
  short* KT  = (short*)(ws + off); off += (size_t)VOCAB * D_DIM * 2;   // 64 MB  bf16 K^T [d][v]
  short* Wb  = (short*)(ws + off); off += (size_t)D_DIM * D_DIM * 2;   //  2 MB  bf16 W
  short* P   = (short*)(ws + off); off += (size_t)ROWS * CHUNK * 2;    // 26 MB  bf16 P slab
  float* num = (float*)(ws + off); off += (size_t)ROWS * D_DIM * 4;    // 16 MB  fp32 numerator
  float* den = (float*)(ws + off); off += (size_t)ROWS * 4;            // 16 KB  fp32 denominator
  float* pre = (float*)P;   // reuse P slab for pre-LN buffer (16 MB <= 26 MB)
  short* Rb  = Q;           // reuse Q region for reprogrammed bf16 (written after last GEMM1)

  hipMemsetAsync(den, 0, ROWS * sizeof(float), stream);
  hipMemsetAsync(num, 0, (size_t)ROWS * D_DIM * sizeof(float), stream);

  k_cvt<<<ROWS * D_DIM / 4 / 256, 256, 0, stream>>>(patch, Q, ROWS * D_DIM / 4);
  k_cvt<<<VOCAB * D_DIM / 4 / 256, 256, 0, stream>>>(proto, Kb, VOCAB * D_DIM / 4);
  k_cvt<<<D_DIM * D_DIM / 4 / 256, 256, 0, stream>>>(W, Wb, D_DIM * D_DIM / 4);
  k_transpose<<<dim3(VOCAB / 32, D_DIM / 32), dim3(32, 8), 0, stream>>>(proto, KT, VOCAB, D_DIM);

  for (int c = 0; c < NCHUNK; ++c) {
    // P = exp(Q @ K_chunk^T), den += rowsum  — M=4096 N=3200 K=1024
    k_gemm<<<dim3(CHUNK / 128, ROWS / 128, 1), 256, 0, stream>>>(
        Q, D_DIM, Kb + (size_t)c * CHUNK * D_DIM, D_DIM, D_DIM, 0,
        P, CHUNK, den, nullptr, nullptr, nullptr, nullptr);
    // num += P @ K_chunk — M=4096 N=1024 K=3200, split-K=2 (atomicAdd epilogue)
    k_gemm<<<dim3(D_DIM / 128, ROWS / 128, 2), 256, 0, stream>>>(
        P, CHUNK, KT + (size_t)c * CHUNK, VOCAB, CHUNK / 2, 1,
        nullptr, 0, nullptr, num, nullptr, nullptr, nullptr);
  }

  k_div<<<ROWS * D_DIM / 4 / 256, 256, 0, stream>>>(num, den, Rb);

  // pre = reprog @ W^T + b + patch — M=4096 N=1024 K=1024
  k_gemm<<<dim3(D_DIM / 128, ROWS / 128, 1), 256, 0, stream>>>(
      Rb, D_DIM, Wb, D_DIM, D_DIM, 2,
      nullptr, 0, nullptr, nullptr, bvec, patch, pre);

  k_ln<<<ROWS, 256, 0, stream>>>(pre, gamma, beta, out);
}